// Round 4
// baseline (238.058 us; speedup 1.0000x reference)
//
#include <hip/hip_runtime.h>

// Problem constants: B=4, N=32, R=64, H=480, W=640, fp32 throughout.
#define BDIM 4
#define NOBJ 32
#define RREL 64
#define HW 307200           // 480*640
#define HW4 (HW / 4)        // 76800 float4 per (b,n) plane
#define CH 15               // chunks per plane: 76800/15 = 5120 exactly
#define CHUNK4 (HW4 / CH)   // 5120 float4 per chunk -> 20 per thread exactly
#define BN (BDIM * NOBJ)    // 128
#define NBLK (BN * CH)      // 1920 blocks (<= 2048 co-resident at 8/CU)
#define BR (BDIM * RREL)    // 256 relations

// Kernel 1: per-(b,n,chunk) masked-depth partial sum + pixel count.
// No atomics, no zero-init: each block writes its own d_ws slot.
// c-major block order: the 128 blocks sharing a chunk index are
// dispatch-adjacent (depth chunks stay L2-resident across the 32 masks).
// Plain cached loads (NT hint removed this round — A/B test).
__global__ __launch_bounds__(256) void rdl_mask_stats(
    const float* __restrict__ depth, const float* __restrict__ masks,
    float2* __restrict__ part)
{
    const int blk = blockIdx.x;
    const int c   = blk >> 7;          // 0..14
    const int bn  = blk & (BN - 1);    // 0..127
    const int b   = bn >> 5;           // 0..3

    const float4* __restrict__ mp =
        (const float4*)masks + (size_t)bn * HW4 + (size_t)c * CHUNK4;
    const float4* __restrict__ dp =
        (const float4*)depth + (size_t)b * HW4 + (size_t)c * CHUNK4;

    const int t = threadIdx.x;
    float s = 0.0f;
    float k = 0.0f;
    #pragma unroll 4
    for (int j = 0; j < 20; ++j) {     // 20 * 256 == CHUNK4, no tail
        const float4 m = mp[t + j * 256];
        const float4 d = dp[t + j * 256];
        if (m.x > 0.5f) { s += d.x; k += 1.0f; }
        if (m.y > 0.5f) { s += d.y; k += 1.0f; }
        if (m.z > 0.5f) { s += d.z; k += 1.0f; }
        if (m.w > 0.5f) { s += d.w; k += 1.0f; }
    }

    // wave(64) shuffle reduction, then cross-wave via LDS
    for (int off = 32; off > 0; off >>= 1) {
        s += __shfl_down(s, off, 64);
        k += __shfl_down(k, off, 64);
    }
    __shared__ float ls[4], lk[4];
    const int lane = t & 63;
    const int wave = t >> 6;
    if (lane == 0) { ls[wave] = s; lk[wave] = k; }
    __syncthreads();
    if (t == 0) {
        part[blk] = make_float2(ls[0] + ls[1] + ls[2] + ls[3],
                                lk[0] + lk[1] + lk[2] + lk[3]);
    }
}

// Kernel 2: one block. Fold the 1920 partials into d_obj/valid (128 entries),
// then one relation per thread (BR == 256 == blockDim), reduce, guarded mean.
__global__ __launch_bounds__(256) void rdl_loss(
    const float2* __restrict__ part,
    const int* __restrict__ subj, const int* __restrict__ obj,
    const int* __restrict__ rel, const float* __restrict__ conf,
    float* __restrict__ out)
{
    __shared__ float dobj[BN];
    __shared__ int   vobj[BN];
    const int t = threadIdx.x;
    if (t < BN) {
        float s = 0.0f, k = 0.0f;
        #pragma unroll
        for (int c = 0; c < CH; ++c) {       // part[c*BN + t]: coalesced per c
            const float2 p = part[c * BN + t];
            s += p.x; k += p.y;
        }
        dobj[t] = s / fmaxf(k, 1.0f);
        vobj[t] = (k >= 20.0f) ? 1 : 0;
    }
    __syncthreads();

    float total;
    int   count;
    {
        const int b  = t / RREL;
        const int rt = rel[t];
        const int si = subj[t];
        const int oi = obj[t];
        const int ia = (rt == 1) ? oi : si;   // sA
        const int ib = (rt == 1) ? si : oi;   // sB
        const float dA = dobj[b * NOBJ + ia];
        const float dB = dobj[b * NOBJ + ib];
        const int   v  = vobj[b * NOBJ + ia] & vobj[b * NOBJ + ib];
        const float margin = (rt == 2) ? 0.3f : 0.1f;
        const float coeff  = (rt == 2) ? 1.5f : 1.0f;
        const float viol   = fmaxf(dA - dB + margin, 0.0f);
        total = coeff * conf[t] * (float)v * viol;
        count = v;
    }
    for (int off = 32; off > 0; off >>= 1) {
        total += __shfl_down(total, off, 64);
        count += __shfl_down(count, off, 64);
    }
    __shared__ float ts[4];
    __shared__ int   cs[4];
    const int lane = t & 63;
    const int wave = t >> 6;
    if (lane == 0) { ts[wave] = total; cs[wave] = count; }
    __syncthreads();
    if (t == 0) {
        const float tt = ts[0] + ts[1] + ts[2] + ts[3];
        const int   cc = cs[0] + cs[1] + cs[2] + cs[3];
        out[0] = (cc > 0) ? tt / fmaxf((float)cc, 1.0f) : 0.0f;
    }
}

extern "C" void kernel_launch(void* const* d_in, const int* in_sizes, int n_in,
                              void* d_out, int out_size, void* d_ws, size_t ws_size,
                              hipStream_t stream)
{
    const float* depth = (const float*)d_in[0];  // (B,1,H,W)
    const float* masks = (const float*)d_in[1];  // (B,N,H,W)
    const int*   subj  = (const int*)d_in[2];    // (B,R)
    const int*   obj   = (const int*)d_in[3];    // (B,R)
    const int*   rel   = (const int*)d_in[4];    // (B,R)
    const float* conf  = (const float*)d_in[5];  // (B,R)
    float*       out   = (float*)d_out;

    float2* part = (float2*)d_ws;                // NBLK float2 partials

    rdl_mask_stats<<<NBLK, 256, 0, stream>>>(depth, masks, part);
    rdl_loss<<<1, 256, 0, stream>>>(part, subj, obj, rel, conf, out);
}

// Round 5
// 230.219 us; speedup vs baseline: 1.0341x; 1.0341x over previous
//
#include <hip/hip_runtime.h>

// Problem constants: B=4, N=32, R=64, H=480, W=640, fp32 throughout.
#define BDIM 4
#define NOBJ 32
#define RREL 64
#define HW 307200           // 480*640
#define HW4 (HW / 4)        // 76800 float4 per (b,n) plane
#define CH 15               // chunks per plane: 76800/15 = 5120 exactly
#define CHUNK4 (HW4 / CH)   // 5120 float4 per chunk -> 20 per thread exactly
#define BN (BDIM * NOBJ)    // 128
#define NBLK (BN * CH)      // 1920 blocks
#define BR (BDIM * RREL)    // 256 relations

// native clang vector type — required by __builtin_nontemporal_load
typedef float vfloat4 __attribute__((ext_vector_type(4)));

// Kernel 1: per-(b,n,chunk) masked-depth partial sum + pixel count.
// No atomics, no zero-init: each block writes its own d_ws slot.
// c-major block order: the 128 blocks sharing a chunk index are
// dispatch-adjacent (depth chunks stay L2-resident across the 32 masks).
// Masks (157 MB, single-use) streamed with NT hint to protect L2 for depth
// (4.9 MB, re-read 32x) — Round 3 vs 4 A/B showed NT worth ~9 us.
__global__ __launch_bounds__(256) void rdl_mask_stats(
    const float* __restrict__ depth, const float* __restrict__ masks,
    float2* __restrict__ part)
{
    const int blk = blockIdx.x;
    const int c   = blk >> 7;          // 0..14
    const int bn  = blk & (BN - 1);    // 0..127
    const int b   = bn >> 5;           // 0..3

    const vfloat4* __restrict__ mp =
        (const vfloat4*)masks + (size_t)bn * HW4 + (size_t)c * CHUNK4;
    const vfloat4* __restrict__ dp =
        (const vfloat4*)depth + (size_t)b * HW4 + (size_t)c * CHUNK4;

    const int t = threadIdx.x;
    float s = 0.0f;
    float k = 0.0f;
    #pragma unroll 4
    for (int j = 0; j < 20; ++j) {     // 20 * 256 == CHUNK4, no tail
        const vfloat4 m = __builtin_nontemporal_load(&mp[t + j * 256]);
        const vfloat4 d = dp[t + j * 256];
        if (m.x > 0.5f) { s += d.x; k += 1.0f; }
        if (m.y > 0.5f) { s += d.y; k += 1.0f; }
        if (m.z > 0.5f) { s += d.z; k += 1.0f; }
        if (m.w > 0.5f) { s += d.w; k += 1.0f; }
    }

    // wave(64) shuffle reduction, then cross-wave via LDS
    for (int off = 32; off > 0; off >>= 1) {
        s += __shfl_down(s, off, 64);
        k += __shfl_down(k, off, 64);
    }
    __shared__ float ls[4], lk[4];
    const int lane = t & 63;
    const int wave = t >> 6;
    if (lane == 0) { ls[wave] = s; lk[wave] = k; }
    __syncthreads();
    if (t == 0) {
        part[blk] = make_float2(ls[0] + ls[1] + ls[2] + ls[3],
                                lk[0] + lk[1] + lk[2] + lk[3]);
    }
}

// Kernel 2: one block. Fold the 1920 partials into d_obj/valid (128 entries),
// then one relation per thread (BR == 256 == blockDim), reduce, guarded mean.
__global__ __launch_bounds__(256) void rdl_loss(
    const float2* __restrict__ part,
    const int* __restrict__ subj, const int* __restrict__ obj,
    const int* __restrict__ rel, const float* __restrict__ conf,
    float* __restrict__ out)
{
    __shared__ float dobj[BN];
    __shared__ int   vobj[BN];
    const int t = threadIdx.x;
    if (t < BN) {
        float s = 0.0f, k = 0.0f;
        #pragma unroll
        for (int c = 0; c < CH; ++c) {       // part[c*BN + t]: coalesced per c
            const float2 p = part[c * BN + t];
            s += p.x; k += p.y;
        }
        dobj[t] = s / fmaxf(k, 1.0f);
        vobj[t] = (k >= 20.0f) ? 1 : 0;
    }
    __syncthreads();

    float total;
    int   count;
    {
        const int b  = t / RREL;
        const int rt = rel[t];
        const int si = subj[t];
        const int oi = obj[t];
        const int ia = (rt == 1) ? oi : si;   // sA
        const int ib = (rt == 1) ? si : oi;   // sB
        const float dA = dobj[b * NOBJ + ia];
        const float dB = dobj[b * NOBJ + ib];
        const int   v  = vobj[b * NOBJ + ia] & vobj[b * NOBJ + ib];
        const float margin = (rt == 2) ? 0.3f : 0.1f;
        const float coeff  = (rt == 2) ? 1.5f : 1.0f;
        const float viol   = fmaxf(dA - dB + margin, 0.0f);
        total = coeff * conf[t] * (float)v * viol;
        count = v;
    }
    for (int off = 32; off > 0; off >>= 1) {
        total += __shfl_down(total, off, 64);
        count += __shfl_down(count, off, 64);
    }
    __shared__ float ts[4];
    __shared__ int   cs[4];
    const int lane = t & 63;
    const int wave = t >> 6;
    if (lane == 0) { ts[wave] = total; cs[wave] = count; }
    __syncthreads();
    if (t == 0) {
        const float tt = ts[0] + ts[1] + ts[2] + ts[3];
        const int   cc = cs[0] + cs[1] + cs[2] + cs[3];
        out[0] = (cc > 0) ? tt / fmaxf((float)cc, 1.0f) : 0.0f;
    }
}

extern "C" void kernel_launch(void* const* d_in, const int* in_sizes, int n_in,
                              void* d_out, int out_size, void* d_ws, size_t ws_size,
                              hipStream_t stream)
{
    const float* depth = (const float*)d_in[0];  // (B,1,H,W)
    const float* masks = (const float*)d_in[1];  // (B,N,H,W)
    const int*   subj  = (const int*)d_in[2];    // (B,R)
    const int*   obj   = (const int*)d_in[3];    // (B,R)
    const int*   rel   = (const int*)d_in[4];    // (B,R)
    const float* conf  = (const float*)d_in[5];  // (B,R)
    float*       out   = (float*)d_out;

    float2* part = (float2*)d_ws;                // NBLK float2 partials

    rdl_mask_stats<<<NBLK, 256, 0, stream>>>(depth, masks, part);
    rdl_loss<<<1, 256, 0, stream>>>(part, subj, obj, rel, conf, out);
}